// Round 10
// baseline (191.453 us; speedup 1.0000x reference)
//
#include <hip/hip_runtime.h>

#define HID 50
#define TSTEPS 256
#define L2E 1.44269504088896340736f

#if __has_builtin(__builtin_amdgcn_exp2f)
#define EXP2(x) __builtin_amdgcn_exp2f(x)
#else
#define EXP2(x) exp2f(x)
#endif

typedef __attribute__((ext_vector_type(8))) _Float16 half8;
typedef __attribute__((ext_vector_type(4))) float f32x4;
typedef __attribute__((ext_vector_type(4))) int int4v;

static __device__ __forceinline__ f32x4 MF16(half8 a, half8 b, f32x4 c) {
    return __builtin_amdgcn_mfma_f32_16x16x32_f16(a, b, c, 0, 0, 0);
}
static __device__ __forceinline__ float sig2(float a) {          // 1/(1+2^a)
    return __builtin_amdgcn_rcpf(1.0f + EXP2(a));
}
static __device__ __forceinline__ float fast_tanh(float x) {
    return 1.0f - 2.0f * sig2(2.0f * L2E * x);
}
static __device__ __forceinline__ float bperm(int idx, float v) {
    return __int_as_float(__builtin_amdgcn_ds_bpermute(idx, __float_as_int(v)));
}
static __device__ __forceinline__ unsigned h16(float v) {        // f32 -> fp16 bits (RTNE)
    _Float16 h = (_Float16)v;
    return (unsigned)__builtin_bit_cast(unsigned short, h);
}

// Wave-local hybrid LSTM: 1 wave = 4 samples, no barriers, no LDS storage.
// K-slot map (identity): slot u<50 = h[u]; 50=x_hi, 51=x_lo, 52=1.0(bias), 53+=0.
// Unit ownership: unit u -> lane 16*(u&3) + s + 4*((u>>3)&3), reg j=2*(u>>5)+((u>>2)&1).
// Cell select: lane (qs,G), o=qs>>2 owns tiles {2o, 2o+1, 8+2o, 9+2o} (phantoms >12).
__global__ __launch_bounds__(64, 1) void hybrid_lstm_wl(
    const float* __restrict__ x,      // [B,256,1]
    const float* __restrict__ W_ih,   // [200,1]
    const float* __restrict__ W_hh,   // [200,50]
    const float* __restrict__ b_ih,   // [200]
    const float* __restrict__ b_hh,   // [200]
    const float* __restrict__ Wp,     // [4,50]
    const float* __restrict__ bp,     // [4]
    const float* __restrict__ qw,     // [2,4,3]
    const float* __restrict__ Wo,     // [1,4]
    const float* __restrict__ bo,     // [1]
    float* __restrict__ out)          // [B,1]
{
    const int lane = threadIdx.x & 63;
    const int qs = lane & 15;
    const int G  = lane >> 4;
    const int s  = qs & 3;            // sample (B cols replicate mod 4)
    const int o  = qs >> 2;           // dup-group / cell-owner coordinate

    // ---------- A fragments: 13 tiles x 2 K-chunks, gate-scaled fp16 ----------
    // tile T row qs -> unit uA = 4T + o, gate = qs&3 (i,f,g,o); K elem r: slot 32c+8G+r
    half8 Ah[13][2];
    {
        const int gate = qs & 3;
        const float sc = (gate == 2) ? 2.0f * L2E : -L2E;
#pragma unroll
        for (int T = 0; T < 13; ++T) {
            const int uA = 4 * T + o;
            const bool vr = (uA < HID);
            const int orow = gate * HID + (vr ? uA : 0);
#pragma unroll
            for (int c = 0; c < 2; ++c) {
#pragma unroll
                for (int r = 0; r < 8; ++r) {
                    const int k = 32 * c + 8 * G + r;
                    float v = 0.0f;
                    if (vr) {
                        if (k < HID)                 v = sc * W_hh[orow * HID + k];
                        else if (k == 50 || k == 51) v = sc * W_ih[orow];
                        else if (k == 52)            v = sc * (b_ih[orow] + b_hh[orow]);
                    }
                    Ah[T][c][r] = (_Float16)v;
                }
            }
        }
    }

    // bpermute gather indices: slot elem e (unit 32c+8G+4b+m, m=e&3) lives at
    // lane 16m + s + 4G, register hreg[2c+b]
    int idxm[4];
#pragma unroll
    for (int m = 0; m < 4; ++m) idxm[m] = (16 * m + s + 4 * G) * 4;

    const bool ob0 = (o & 1) != 0;
    const bool ob1 = (o & 2) != 0;

    float hreg[4] = {0.0f, 0.0f, 0.0f, 0.0f};
    float cst[4]  = {0.0f, 0.0f, 0.0f, 0.0f};
    const f32x4 zq = {0.0f, 0.0f, 0.0f, 0.0f};

    const float* xg = x + (size_t)(blockIdx.x * 4 + s) * TSTEPS;
    float4 xq = *(const float4*)xg;

#pragma unroll 1
    for (int t4 = 0; t4 < TSTEPS; t4 += 4) {
        const int tn = (t4 + 4 < TSTEPS) ? (t4 + 4) : (TSTEPS - 4);
        const float4 xqn = *(const float4*)(xg + tn);   // prefetch next group
#pragma unroll
        for (int kk = 0; kk < 4; ++kk) {
            const float xt = (kk == 0) ? xq.x : (kk == 1) ? xq.y : (kk == 2) ? xq.z : xq.w;
            // x hi/lo split (slots 50,51), packed as one dword
            const _Float16 xh = (_Float16)xt;
            const unsigned xdw = h16(xt) | (h16(xt - (float)xh) << 16);

            // ---- B build: 16 bpermutes -> fp16 pack ----
            unsigned dw0[4], dw1[4];
#pragma unroll
            for (int d = 0; d < 4; ++d) {
                const int e0 = 2 * d, e1 = 2 * d + 1;
                const float a0 = bperm(idxm[e0 & 3], hreg[(e0 >> 2)]);
                const float a1 = bperm(idxm[e1 & 3], hreg[(e1 >> 2)]);
                dw0[d] = h16(a0) | (h16(a1) << 16);
                const float b0 = bperm(idxm[e0 & 3], hreg[2 + (e0 >> 2)]);
                const float b1 = bperm(idxm[e1 & 3], hreg[2 + (e1 >> 2)]);
                dw1[d] = h16(b0) | (h16(b1) << 16);
            }
            dw1[1] = (G == 2) ? xdw : dw1[1];           // slots 50,51 = x_hi,x_lo
            dw1[2] = (G == 2) ? 0x00003C00u : dw1[2];   // slot 52 = 1.0, slot 53 = 0
            const int4v i0 = {(int)dw0[0], (int)dw0[1], (int)dw0[2], (int)dw0[3]};
            const int4v i1 = {(int)dw1[0], (int)dw1[1], (int)dw1[2], (int)dw1[3]};
            const half8 bh0 = __builtin_bit_cast(half8, i0);
            const half8 bh1 = __builtin_bit_cast(half8, i1);

            // ---- 13 tile MFMAs (depth-2 chains, independent across tiles) ----
            f32x4 acc[13];
#pragma unroll
            for (int T = 0; T < 13; ++T) acc[T] = MF16(Ah[T][0], bh0, zq);
#pragma unroll
            for (int T = 0; T < 13; ++T) acc[T] = MF16(Ah[T][1], bh1, acc[T]);

            // ---- select this lane's 4 cells (static regs + cndmask on o-bits) ----
            f32x4 cell[4];
#pragma unroll
            for (int r = 0; r < 4; ++r) {
                const float a01 = ob0 ? acc[2][r]  : acc[0][r];
                const float a23 = ob0 ? acc[6][r]  : acc[4][r];
                cell[0][r] = ob1 ? a23 : a01;                    // T = 2o
                const float b01 = ob0 ? acc[3][r]  : acc[1][r];
                const float b23 = ob0 ? acc[7][r]  : acc[5][r];
                cell[1][r] = ob1 ? b23 : b01;                    // T = 2o+1
                const float c01 = ob0 ? acc[10][r] : acc[8][r];
                const float c23 = ob0 ? acc[8][r]  : acc[12][r]; // o=3 phantom
                cell[2][r] = ob1 ? c23 : c01;                    // T = 8+2o
                const float d01 = ob0 ? acc[11][r] : acc[9][r];
                cell[3][r] = ob1 ? acc[9][r] : d01;              // T = 9+2o (o>=2 ph)
            }

            // ---- gates (exp2-native; a0,a1,a3 = -log2e*pre, a2 = 2log2e*pre) ----
#pragma unroll
            for (int j = 0; j < 4; ++j) {
                const float ig = sig2(cell[j][0]);
                const float fg = sig2(cell[j][1]);
                const float gg = 1.0f - 2.0f * sig2(cell[j][2]);
                const float og = sig2(cell[j][3]);
                cst[j] = fmaf(fg, cst[j], ig * gg);
                hreg[j] = og * fast_tanh(cst[j]);
            }
        }
        xq = xqn;
    }

    // ---------- epilogue: angles + 4-qubit circuit (4 samples in one wave) ----------
    // bp seeded ONLY on G==0 lanes: the xor-16/32 reduction sums the 4 G-group
    // partials, so seeding every lane would count bp 4x (the R9 bug).
    float ang[4];
#pragma unroll
    for (int q = 0; q < 4; ++q) ang[q] = (G == 0) ? bp[q] : 0.0f;
#pragma unroll
    for (int c = 0; c < 2; ++c) {
#pragma unroll
        for (int e = 0; e < 8; ++e) {
            const int u = 32 * c + 8 * G + e;
            const float hv = bperm(idxm[e & 3], hreg[2 * c + (e >> 2)]);
#pragma unroll
            for (int q = 0; q < 4; ++q) {
                const float w = (u < HID) ? Wp[q * HID + u] : 0.0f;
                ang[q] = fmaf(w, hv, ang[q]);
            }
        }
    }
#pragma unroll
    for (int q = 0; q < 4; ++q) {     // reduce across the 4 G-lane groups
        ang[q] += __shfl_xor(ang[q], 16);
        ang[q] += __shfl_xor(ang[q], 32);
    }
    // rebroadcast: circuit lane-group sm = lane>>4 processes sample sm
    const int sm  = lane >> 4;
    const int ql  = lane & 15;
    const int grp = lane & 48;
    const int idxg = sm * 4;          // lane sm holds ang for sample sm (qs=sm, G=0)
    float angc[4];
#pragma unroll
    for (int q = 0; q < 4; ++q)
        angc[q] = fast_tanh(bperm(idxg, ang[q])) * 1.57079632679489662f;

    float ar = (ql == 0) ? 1.0f : 0.0f;
    float ai = 0.0f;

    // RX embedding
#pragma unroll
    for (int wq = 0; wq < 4; ++wq) {
        const int mask = 8 >> wq;
        float s_, c_;
        __sincosf(0.5f * angc[wq], &s_, &c_);
        const float pr = __shfl_xor(ar, mask);
        const float pi = __shfl_xor(ai, mask);
        const float nr = c_ * ar + s_ * pi;
        const float ni = c_ * ai - s_ * pr;
        ar = nr; ai = ni;
    }
    // StronglyEntanglingLayers
#pragma unroll
    for (int l = 0; l < 2; ++l) {
#pragma unroll
        for (int wq = 0; wq < 4; ++wq) {
            const float phi = qw[(l * 4 + wq) * 3 + 0];
            const float th  = qw[(l * 4 + wq) * 3 + 1];
            const float om  = qw[(l * 4 + wq) * 3 + 2];
            float st_, ct_, sa, ca, sb, cb;
            __sincosf(0.5f * th, &st_, &ct_);
            __sincosf(0.5f * (phi + om), &sa, &ca);
            __sincosf(0.5f * (phi - om), &sb, &cb);
            const int mask = 8 >> wq;
            const bool bit = (ql & mask) != 0;
            const float dr  = ca * ct_;
            const float di  = (bit ? sa : -sa) * ct_;
            const float orr = (bit ? cb : -cb) * st_;
            const float oi  = -sb * st_;
            const float pr = __shfl_xor(ar, mask);
            const float pi = __shfl_xor(ai, mask);
            const float nr = dr * ar - di * ai + orr * pr - oi * pi;
            const float ni = dr * ai + di * ar + orr * pi + oi * pr;
            ar = nr; ai = ni;
        }
        const int r = (l % 3) + 1;
#pragma unroll
        for (int wq = 0; wq < 4; ++wq) {
            const int mc  = 8 >> wq;
            const int mt  = 8 >> ((wq + r) % 4);
            const int src = (ql & mc) ? (ql ^ mt) : ql;
            ar = __shfl(ar, grp | src);
            ai = __shfl(ai, grp | src);
        }
    }
    const float prob = ar * ar + ai * ai;
    float coeff = 0.0f;
#pragma unroll
    for (int wq = 0; wq < 4; ++wq) {
        const float sgn = (ql & (8 >> wq)) ? -1.0f : 1.0f;
        coeff = fmaf(sgn, Wo[wq], coeff);
    }
    float v = prob * coeff;
    v += __shfl_xor(v, 1);
    v += __shfl_xor(v, 2);
    v += __shfl_xor(v, 4);
    v += __shfl_xor(v, 8);
    if (ql == 0) out[blockIdx.x * 4 + sm] = v + bo[0];
}

extern "C" void kernel_launch(void* const* d_in, const int* in_sizes, int n_in,
                              void* d_out, int out_size, void* d_ws, size_t ws_size,
                              hipStream_t stream) {
    const float* x    = (const float*)d_in[0];
    const float* W_ih = (const float*)d_in[1];
    const float* W_hh = (const float*)d_in[2];
    const float* b_ih = (const float*)d_in[3];
    const float* b_hh = (const float*)d_in[4];
    const float* Wp   = (const float*)d_in[5];
    const float* bp   = (const float*)d_in[6];
    const float* qw   = (const float*)d_in[7];
    const float* Wo   = (const float*)d_in[8];
    const float* bo   = (const float*)d_in[9];
    float* out = (float*)d_out;

    const int B = in_sizes[0] / TSTEPS;
    hybrid_lstm_wl<<<B / 4, 64, 0, stream>>>(x, W_ih, W_hh, b_ih, b_hh,
                                             Wp, bp, qw, Wo, bo, out);
}

// Round 11
// 179.628 us; speedup vs baseline: 1.0658x; 1.0658x over previous
//
#include <hip/hip_runtime.h>

#define HID 50
#define TSTEPS 256
#define SPB 16              // 8 samples group A (cols 0-7) + 8 group B (cols 8-15)
#define NW 7                // waves per block, 2 M-tiles each: 56 units >= 50
#define THREADS (NW * 64)
#define XSTRIDE 260         // floats per sample row in x_lds (pad incl. t=256..259)

#if __has_builtin(__builtin_amdgcn_exp2f)
#define EXP2(x) __builtin_amdgcn_exp2f(x)
#else
#define EXP2(x) exp2f(x)
#endif
#define L2E 1.44269504088896340736f

typedef __attribute__((ext_vector_type(8))) _Float16 half8;
typedef __attribute__((ext_vector_type(4))) float f32x4;

static __device__ __forceinline__ f32x4 MF16(half8 a, half8 b, f32x4 c) {
    return __builtin_amdgcn_mfma_f32_16x16x32_f16(a, b, c, 0, 0, 0);
}
static __device__ __forceinline__ float sig2(float a) {          // 1/(1+2^a)
    return __builtin_amdgcn_rcpf(1.0f + EXP2(a));
}
static __device__ __forceinline__ float fast_tanh(float x) {
    return 1.0f - 2.0f * sig2(2.0f * L2E * x);
}

// Dual-group staggered LSTM: one MFMA's 16 columns carry group A (cols 0-7)
// and group B (cols 8-15) at alternating phases. Each group's gate chain
// hides the other group's write->barrier->reload->MFMA latency.
// h table (R5-verified conflict-free broadcast layout, identity slots):
//   chunk table c holds units 32c..32c+31; entry(u,col) =
//   h_tab[u>>5][ (((u>>3)&3)*16 + col)*8 + (u&7) ]
//   B-frag read for chunk c = 16B at lane*8 (linear, conflict-free).
__global__ __launch_bounds__(THREADS) void hybrid_lstm_dual(
    const float* __restrict__ x,      // [B,256,1]
    const float* __restrict__ W_ih,   // [200,1]
    const float* __restrict__ W_hh,   // [200,50]
    const float* __restrict__ b_ih,   // [200]
    const float* __restrict__ b_hh,   // [200]
    const float* __restrict__ Wp,     // [4,50]
    const float* __restrict__ bp,     // [4]
    const float* __restrict__ qw,     // [2,4,3]
    const float* __restrict__ Wo,     // [1,4]
    const float* __restrict__ bo,     // [1]
    float* __restrict__ out)          // [B,1]
{
    __shared__ __align__(16) float x_lds[SPB * XSTRIDE];
    __shared__ __align__(16) _Float16 h_tab[2][512];

    const int tid  = threadIdx.x;
    const int wid  = tid >> 6;        // 0..6
    const int lane = tid & 63;
    const int qs   = lane & 15;       // MFMA column (sample col)
    const int g2   = lane >> 4;       // K-group / C-row-group

    // ---------- prologue: zero h table, stage x (+zero pad) ----------
    {
        unsigned* hz = (unsigned*)&h_tab[0][0];
        for (int i = tid; i < 512; i += THREADS) hz[i] = 0u;
        const float* xg = x + (size_t)blockIdx.x * SPB * TSTEPS;
        for (int i = tid; i < SPB * TSTEPS; i += THREADS)
            x_lds[(i >> 8) * XSTRIDE + (i & 255)] = xg[i];
        for (int i = tid; i < SPB * 4; i += THREADS)
            x_lds[(i >> 2) * XSTRIDE + 256 + (i & 3)] = 0.0f;
    }

    // ---------- A fragments: 2 tiles/wave, gate-scaled fp16, identity K-map ----------
    // tile ti: M-row qs -> unit uA = 8*wid + 4*ti + (qs>>2), gate = qs&3 (i,f,g,o)
    // K elem (c,r): unit k = 32c + 8*g2 + r.  scale: i,f,o * -log2e ; g * 2*log2e
    half8 Ah[2][2];
    {
        const int gate = qs & 3;
        const float sc = (gate == 2) ? 2.0f * L2E : -L2E;
#pragma unroll
        for (int ti = 0; ti < 2; ++ti) {
            const int uA  = 8 * wid + 4 * ti + (qs >> 2);
            const bool vr = (uA < HID);
            const int orow = gate * HID + (vr ? uA : 0);
#pragma unroll
            for (int c = 0; c < 2; ++c) {
#pragma unroll
                for (int r = 0; r < 8; ++r) {
                    const int k = 32 * c + 8 * g2 + r;
                    float v = 0.0f;
                    if (vr && k < HID) v = sc * W_hh[orow * HID + k];
                    Ah[ti][c][r] = (_Float16)v;
                }
            }
        }
    }

    // acc-init consts per tile: acc_ti[reg] = gate 'reg' of unit 8*wid + 4*ti + g2
    // invalid units: zero weights/bias -> h stays identically 0 (finite).
    float wihc[2][4], bsumc[2][4];
#pragma unroll
    for (int ti = 0; ti < 2; ++ti) {
        const int uC  = 8 * wid + 4 * ti + g2;
        const bool cv = (uC < HID);
#pragma unroll
        for (int reg = 0; reg < 4; ++reg) {
            const float sc = (reg == 2) ? 2.0f * L2E : -L2E;
            const int orow = reg * HID + (cv ? uC : 0);
            wihc[ti][reg]  = cv ? sc * W_ih[orow] : 0.0f;
            bsumc[ti][reg] = cv ? sc * (b_ih[orow] + b_hh[orow]) : 0.0f;
        }
    }

    // post-repack cell: lane owns sample-col s_l (A) / s_l+8 (B), unit u_l
    const int s_l  = qs & 7;
    const bool hi8 = (qs >= 8);
    const int u_l  = 8 * wid + 4 * (qs >> 3) + g2;    // 0..55
    _Float16* const wA = &h_tab[u_l >> 5][(((u_l >> 3) & 3) * 16 + s_l) * 8 + (u_l & 7)];
    _Float16* const wB = wA + 64;                     // col + 8

    __syncthreads();

    // B-operand fragments (registers): lane(qs,g2) holds B[k=8g2+r (+32c), col=qs]
    half8 bh0 = {}, bh1 = {};                         // h(-1) = 0 both groups
    float cstA = 0.0f, cstB = 0.0f;

    // accA(0): h-part is zero -> exact init only
    f32x4 aA0, aA1;
    {
        const float x0 = x_lds[qs * XSTRIDE + 0];
#pragma unroll
        for (int reg = 0; reg < 4; ++reg) {
            aA0[reg] = fmaf(wihc[0][reg], x0, bsumc[0][reg]);
            aA1[reg] = fmaf(wihc[1][reg], x0, bsumc[1][reg]);
        }
    }

#pragma unroll 1
    for (int t = 0; t < TSTEPS; ++t) {
        // ---- gates A(t)  (covers loop-carried B-col reload latency) ----
        f32x4 cellA;
#pragma unroll
        for (int reg = 0; reg < 4; ++reg) {
            const float rm = __shfl_xor(aA1[reg], 8);   // tile1 accs to hi lanes
            cellA[reg] = hi8 ? rm : aA0[reg];
        }
        const float iA = sig2(cellA[0]);
        const float fA = sig2(cellA[1]);
        const float gA = 1.0f - 2.0f * sig2(cellA[2]);
        const float oA = sig2(cellA[3]);
        cstA = fmaf(fA, cstA, iA * gA);
        const float hA = oA * fast_tanh(cstA);

        // ---- accB(t) = init + MFMA  (B-cols = hB(t-1); A-col outputs discarded) ----
        const float xB = x_lds[qs * XSTRIDE + t];
        f32x4 aB0, aB1;
#pragma unroll
        for (int reg = 0; reg < 4; ++reg) {
            aB0[reg] = fmaf(wihc[0][reg], xB, bsumc[0][reg]);
            aB1[reg] = fmaf(wihc[1][reg], xB, bsumc[1][reg]);
        }
        aB0 = MF16(Ah[0][0], bh0, aB0);
        aB1 = MF16(Ah[1][0], bh0, aB1);
        aB0 = MF16(Ah[0][1], bh1, aB0);
        aB1 = MF16(Ah[1][1], bh1, aB1);

        *wA = (_Float16)hA;                 // hA(t) -> table col s_l
        __syncthreads();
        if (!hi8) {                         // A-col frags reload hA(t)
            bh0 = *(const half8*)(&h_tab[0][0] + lane * 8);
            bh1 = *(const half8*)(&h_tab[1][0] + lane * 8);
        }

        // ---- gates B(t)  (covers A-col reload latency) ----
        f32x4 cellB;
#pragma unroll
        for (int reg = 0; reg < 4; ++reg) {
            const float rm = __shfl_xor(aB0[reg], 8);   // tile0 accs to lo lanes
            cellB[reg] = hi8 ? aB1[reg] : rm;
        }
        const float iB = sig2(cellB[0]);
        const float fB = sig2(cellB[1]);
        const float gB = 1.0f - 2.0f * sig2(cellB[2]);
        const float oB = sig2(cellB[3]);
        cstB = fmaf(fB, cstB, iB * gB);
        const float hB = oB * fast_tanh(cstB);

        // ---- accA(t+1) = init + MFMA  (A-cols = hA(t) just reloaded) ----
        const float xA = x_lds[qs * XSTRIDE + t + 1];   // t=255: pad (discarded)
#pragma unroll
        for (int reg = 0; reg < 4; ++reg) {
            aA0[reg] = fmaf(wihc[0][reg], xA, bsumc[0][reg]);
            aA1[reg] = fmaf(wihc[1][reg], xA, bsumc[1][reg]);
        }
        aA0 = MF16(Ah[0][0], bh0, aA0);
        aA1 = MF16(Ah[1][0], bh0, aA1);
        aA0 = MF16(Ah[0][1], bh1, aA0);
        aA1 = MF16(Ah[1][1], bh1, aA1);

        *wB = (_Float16)hB;                 // hB(t) -> table col s_l+8
        __syncthreads();
        if (hi8) {                          // B-col frags reload hB(t)
            bh0 = *(const half8*)(&h_tab[0][0] + lane * 8);
            bh1 = *(const half8*)(&h_tab[1][0] + lane * 8);
        }
    }

    // ---------- epilogue: angles + 4-qubit circuit, 4 samples per wave (waves 0-3) ----------
    if (wid < 4) {
        const int sm  = 4 * wid + (lane >> 4);   // 0..15
        const int ql  = lane & 15;
        const int grp = lane & 48;

        float ang0 = bp[0], ang1 = bp[1], ang2 = bp[2], ang3 = bp[3];
#pragma unroll
        for (int k = 0; k < HID; ++k) {
            const float hk = (float)h_tab[k >> 5][(((k >> 3) & 3) * 16 + sm) * 8 + (k & 7)];
            ang0 = fmaf(Wp[0 * HID + k], hk, ang0);
            ang1 = fmaf(Wp[1 * HID + k], hk, ang1);
            ang2 = fmaf(Wp[2 * HID + k], hk, ang2);
            ang3 = fmaf(Wp[3 * HID + k], hk, ang3);
        }
        float ang[4];
        ang[0] = fast_tanh(ang0) * 1.57079632679489662f;
        ang[1] = fast_tanh(ang1) * 1.57079632679489662f;
        ang[2] = fast_tanh(ang2) * 1.57079632679489662f;
        ang[3] = fast_tanh(ang3) * 1.57079632679489662f;

        float ar = (ql == 0) ? 1.0f : 0.0f;
        float ai = 0.0f;

        // RX embedding
#pragma unroll
        for (int wq = 0; wq < 4; ++wq) {
            const int mask = 8 >> wq;
            float s_, c_;
            __sincosf(0.5f * ang[wq], &s_, &c_);
            const float pr = __shfl_xor(ar, mask);
            const float pi = __shfl_xor(ai, mask);
            const float nr = c_ * ar + s_ * pi;
            const float ni = c_ * ai - s_ * pr;
            ar = nr; ai = ni;
        }
        // StronglyEntanglingLayers
#pragma unroll
        for (int l = 0; l < 2; ++l) {
#pragma unroll
            for (int wq = 0; wq < 4; ++wq) {
                const float phi = qw[(l * 4 + wq) * 3 + 0];
                const float th  = qw[(l * 4 + wq) * 3 + 1];
                const float om  = qw[(l * 4 + wq) * 3 + 2];
                float st_, ct_, sa, ca, sb, cb;
                __sincosf(0.5f * th, &st_, &ct_);
                __sincosf(0.5f * (phi + om), &sa, &ca);
                __sincosf(0.5f * (phi - om), &sb, &cb);
                const int mask = 8 >> wq;
                const bool bit = (ql & mask) != 0;
                const float dr  = ca * ct_;
                const float di  = (bit ? sa : -sa) * ct_;
                const float orr = (bit ? cb : -cb) * st_;
                const float oi  = -sb * st_;
                const float pr = __shfl_xor(ar, mask);
                const float pi = __shfl_xor(ai, mask);
                const float nr = dr * ar - di * ai + orr * pr - oi * pi;
                const float ni = dr * ai + di * ar + orr * pi + oi * pr;
                ar = nr; ai = ni;
            }
            const int r = (l % 3) + 1;
#pragma unroll
            for (int wq = 0; wq < 4; ++wq) {
                const int mc  = 8 >> wq;
                const int mt  = 8 >> ((wq + r) % 4);
                const int src = (ql & mc) ? (ql ^ mt) : ql;
                ar = __shfl(ar, grp | src);
                ai = __shfl(ai, grp | src);
            }
        }
        const float prob = ar * ar + ai * ai;
        float coeff = 0.0f;
#pragma unroll
        for (int wq = 0; wq < 4; ++wq) {
            const float sgn = (ql & (8 >> wq)) ? -1.0f : 1.0f;
            coeff = fmaf(sgn, Wo[wq], coeff);
        }
        float v = prob * coeff;
        v += __shfl_xor(v, 1);
        v += __shfl_xor(v, 2);
        v += __shfl_xor(v, 4);
        v += __shfl_xor(v, 8);
        if (ql == 0) out[blockIdx.x * SPB + sm] = v + bo[0];
    }
}

extern "C" void kernel_launch(void* const* d_in, const int* in_sizes, int n_in,
                              void* d_out, int out_size, void* d_ws, size_t ws_size,
                              hipStream_t stream) {
    const float* x    = (const float*)d_in[0];
    const float* W_ih = (const float*)d_in[1];
    const float* W_hh = (const float*)d_in[2];
    const float* b_ih = (const float*)d_in[3];
    const float* b_hh = (const float*)d_in[4];
    const float* Wp   = (const float*)d_in[5];
    const float* bp   = (const float*)d_in[6];
    const float* qw   = (const float*)d_in[7];
    const float* Wo   = (const float*)d_in[8];
    const float* bo   = (const float*)d_in[9];
    float* out = (float*)d_out;

    const int B = in_sizes[0] / TSTEPS;
    hybrid_lstm_dual<<<B / SPB, THREADS, 0, stream>>>(x, W_ih, W_hh, b_ih, b_hh,
                                                      Wp, bp, qw, Wo, bo, out);
}

// Round 12
// 158.495 us; speedup vs baseline: 1.2079x; 1.1333x over previous
//
#include <hip/hip_runtime.h>

#define HID 50
#define TSTEPS 256
#define SPB 8               // samples per block -> grid 512 -> 2 blocks/CU
#define NW 4                // waves per block, 4 M-tiles each: 256 rows >= 200
#define THREADS (NW * 64)
#define XSTRIDE 260         // floats per sample row in x_lds (16B-aligned)

#if __has_builtin(__builtin_amdgcn_exp2f)
#define EXP2(x) __builtin_amdgcn_exp2f(x)
#else
#define EXP2(x) exp2f(x)
#endif
#define L2E 1.44269504088896340736f

typedef __attribute__((ext_vector_type(8))) _Float16 half8;
typedef __attribute__((ext_vector_type(4))) float f32x4;

static __device__ __forceinline__ f32x4 MF16(half8 a, half8 b, f32x4 c) {
    return __builtin_amdgcn_mfma_f32_16x16x32_f16(a, b, c, 0, 0, 0);
}
static __device__ __forceinline__ float sig2(float a) {          // 1/(1+2^a)
    return __builtin_amdgcn_rcpf(1.0f + EXP2(a));
}
static __device__ __forceinline__ float fast_tanh(float x) {
    return 1.0f - 2.0f * sig2(2.0f * L2E * x);
}

// R8 geometry + R5/R11-verified conflict-free chunk tables + phase stagger.
// h table per buf: 2 chunk tables x 512 fp16. Table c holds units 32c..32c+31.
//   entry(u, col) = (u>>5)*512 + (((u>>3)&3)*16 + col)*8 + (u&7)
//   B-frag read chunk c = 16B at table_c + lane*8  (linear -> conflict-free).
// Cols 8..15 are never written and stay zero (8 samples use cols 0-7).
__global__ __launch_bounds__(THREADS, 2) void hybrid_lstm_stag(
    const float* __restrict__ x,      // [B,256,1]
    const float* __restrict__ W_ih,   // [200,1]
    const float* __restrict__ W_hh,   // [200,50]
    const float* __restrict__ b_ih,   // [200]
    const float* __restrict__ b_hh,   // [200]
    const float* __restrict__ Wp,     // [4,50]
    const float* __restrict__ bp,     // [4]
    const float* __restrict__ qw,     // [2,4,3]
    const float* __restrict__ Wo,     // [1,4]
    const float* __restrict__ bo,     // [1]
    float* __restrict__ out)          // [B,1]
{
    __shared__ __align__(16) float x_lds[SPB * XSTRIDE];
    __shared__ __align__(16) _Float16 h_tab[2][1024];   // [buf][chunk*512 + entry]

    const int tid  = threadIdx.x;
    const int wid  = tid >> 6;        // 0..3
    const int lane = tid & 63;
    const int qs   = lane & 15;       // sample col / A-row-within-tile
    const int g2   = lane >> 4;       // K-group / C-row-group

    // ---------- prologue: zero h tables, stage x ----------
    {
        unsigned* hz = (unsigned*)&h_tab[0][0];
        for (int i = tid; i < 1024; i += THREADS) hz[i] = 0u;
        const float* xg = x + (size_t)blockIdx.x * SPB * TSTEPS;
        for (int i = tid; i < SPB * TSTEPS; i += THREADS)
            x_lds[(i >> 8) * XSTRIDE + (i & 255)] = xg[i];
    }

    // ---------- A fragments: 4 tiles per wave, gate-scaled fp16, identity K-map ----------
    // tile T = 4*wid+ti: A-row qs -> unit uA = 4T + (qs>>2), gate q = qs&3 (i,f,g,o)
    // K element (c,r): unit k = 32c + 8*g2 + r.  scale: i,f,o * -log2e ; g * 2*log2e
    half8 Ah[4][2];
    {
        const int q    = qs & 3;
        const float sc = (q == 2) ? 2.0f * L2E : -L2E;
#pragma unroll
        for (int ti = 0; ti < 4; ++ti) {
            const int uA  = 4 * (4 * wid + ti) + (qs >> 2);
            const bool vr = (uA < HID);
            const int orow = q * HID + (vr ? uA : 0);
#pragma unroll
            for (int c = 0; c < 2; ++c) {
#pragma unroll
                for (int r = 0; r < 8; ++r) {
                    const int k = 32 * c + 8 * g2 + r;
                    float v = 0.0f;
                    if (vr && k < HID) v = sc * W_hh[orow * HID + k];
                    Ah[ti][c][r] = (_Float16)v;
                }
            }
        }
    }

    // acc-init consts per tile (invalid units zeroed -> h stays exactly 0)
    float wihc[4][4], bsumc[4][4];
#pragma unroll
    for (int ti = 0; ti < 4; ++ti) {
        const int uC  = 4 * (4 * wid + ti) + g2;
        const bool cv = (uC < HID);
#pragma unroll
        for (int reg = 0; reg < 4; ++reg) {
            const float sc = (reg == 2) ? 2.0f * L2E : -L2E;
            const int orow = reg * HID + (cv ? uC : 0);
            wihc[ti][reg]  = cv ? sc * W_ih[orow] : 0.0f;
            bsumc[ti][reg] = cv ? sc * (b_ih[orow] + b_hh[orow]) : 0.0f;
        }
    }

    // post-repack cells: lane owns sample col s_l, units u = 16*wid + 8*hi8 + 4j + g2
    const int s_l  = qs & 7;
    const bool hi8 = (qs >= 8);
    const int u0w  = 16 * wid + (hi8 ? 8 : 0) + g2;
    const int u1w  = u0w + 4;
    _Float16* const wpA =
        &h_tab[0][(u0w >> 5) * 512 + (((u0w >> 3) & 3) * 16 + s_l) * 8 + (u0w & 7)];
    _Float16* const wpB =
        &h_tab[0][(u1w >> 5) * 512 + (((u1w >> 3) & 3) * 16 + s_l) * 8 + (u1w & 7)];

    __syncthreads();

    // ---- phase stagger: offset odd blocks by ~832 cy (half of R8's step) so the
    // two co-resident blocks' compute and latency phases interleave ----
    if (blockIdx.x & 1) {
        __builtin_amdgcn_s_sleep(7);   // ~448 cy
        __builtin_amdgcn_s_sleep(6);   // ~384 cy
    }

    float cstA = 0.0f, cstB = 0.0f;
    half8 bh0, bh1;
    auto loadB = [&](int buf) {
        const _Float16* bp_ = &h_tab[buf][0] + lane * 8;
        bh0 = *(const half8*)(bp_);
        bh1 = *(const half8*)(bp_ + 512);
    };

    loadB(1);   // h(-1) = 0 from zeroed buf1

    const float* xrow = &x_lds[s_l * XSTRIDE];

#pragma unroll 1
    for (int t4 = 0; t4 < TSTEPS; t4 += 4) {
        const float4 xq = *(const float4*)(xrow + t4);
#pragma unroll
        for (int k = 0; k < 4; ++k) {
            const float xt = (k == 0) ? xq.x : (k == 1) ? xq.y : (k == 2) ? xq.z : xq.w;
            // acc init = exact fp32 (scaled) bias + W_ih*x_t
            f32x4 a0, a1, a2, a3;
#pragma unroll
            for (int reg = 0; reg < 4; ++reg) {
                a0[reg] = fmaf(wihc[0][reg], xt, bsumc[0][reg]);
                a1[reg] = fmaf(wihc[1][reg], xt, bsumc[1][reg]);
                a2[reg] = fmaf(wihc[2][reg], xt, bsumc[2][reg]);
                a3[reg] = fmaf(wihc[3][reg], xt, bsumc[3][reg]);
            }
            a0 = MF16(Ah[0][0], bh0, a0);
            a1 = MF16(Ah[1][0], bh0, a1);
            a2 = MF16(Ah[2][0], bh0, a2);
            a3 = MF16(Ah[3][0], bh0, a3);
            a0 = MF16(Ah[0][1], bh1, a0);
            a1 = MF16(Ah[1][1], bh1, a1);
            a2 = MF16(Ah[2][1], bh1, a2);
            a3 = MF16(Ah[3][1], bh1, a3);

            // repack: lanes qs>=8 take tiles 2,3 from lane qs-8 -> 2 cells/lane
            f32x4 cA, cB;
#pragma unroll
            for (int reg = 0; reg < 4; ++reg) {
                const float r2 = __shfl_xor(a2[reg], 8);
                const float r3 = __shfl_xor(a3[reg], 8);
                cA[reg] = hi8 ? r2 : a0[reg];
                cB[reg] = hi8 ? r3 : a1[reg];
            }

            // gates, cell A (unit u0w)
            const float iA = sig2(cA[0]);
            const float fA = sig2(cA[1]);
            const float gA = 1.0f - 2.0f * sig2(cA[2]);
            const float oA = sig2(cA[3]);
            cstA = fmaf(fA, cstA, iA * gA);
            const float hA = oA * fast_tanh(cstA);
            // gates, cell B (unit u1w)
            const float iB = sig2(cB[0]);
            const float fB = sig2(cB[1]);
            const float gB = 1.0f - 2.0f * sig2(cB[2]);
            const float oB = sig2(cB[3]);
            cstB = fmaf(fB, cstB, iB * gB);
            const float hB = oB * fast_tanh(cstB);

            const int boff = (k & 1) * 1024;   // static per unrolled k
            wpA[boff] = (_Float16)hA;
            wpB[boff] = (_Float16)hB;
            __syncthreads();
            loadB(k & 1);                      // h(t) for next step
        }
    }

    // ---------- epilogue: angles + 4-qubit circuit, 4 samples per wave (waves 0-1) ----------
    if (wid < 2) {
        const int sm  = 4 * wid + (lane >> 4);   // 0..7
        const int ql  = lane & 15;
        const int grp = lane & 48;

        const _Float16* t1 = &h_tab[1][0];       // h(255) lives in buf1
        float ang0 = bp[0], ang1 = bp[1], ang2 = bp[2], ang3 = bp[3];
#pragma unroll
        for (int kk = 0; kk < HID; ++kk) {
            const int idx = (kk >> 5) * 512 + (((kk >> 3) & 3) * 16 + sm) * 8 + (kk & 7);
            const float hk = (float)t1[idx];
            ang0 = fmaf(Wp[0 * HID + kk], hk, ang0);
            ang1 = fmaf(Wp[1 * HID + kk], hk, ang1);
            ang2 = fmaf(Wp[2 * HID + kk], hk, ang2);
            ang3 = fmaf(Wp[3 * HID + kk], hk, ang3);
        }
        float ang[4];
        ang[0] = fast_tanh(ang0) * 1.57079632679489662f;
        ang[1] = fast_tanh(ang1) * 1.57079632679489662f;
        ang[2] = fast_tanh(ang2) * 1.57079632679489662f;
        ang[3] = fast_tanh(ang3) * 1.57079632679489662f;

        float ar = (ql == 0) ? 1.0f : 0.0f;
        float ai = 0.0f;

        // RX embedding
#pragma unroll
        for (int wq = 0; wq < 4; ++wq) {
            const int mask = 8 >> wq;
            float s_, c_;
            __sincosf(0.5f * ang[wq], &s_, &c_);
            const float pr = __shfl_xor(ar, mask);
            const float pi = __shfl_xor(ai, mask);
            const float nr = c_ * ar + s_ * pi;
            const float ni = c_ * ai - s_ * pr;
            ar = nr; ai = ni;
        }
        // StronglyEntanglingLayers
#pragma unroll
        for (int l = 0; l < 2; ++l) {
#pragma unroll
            for (int wq = 0; wq < 4; ++wq) {
                const float phi = qw[(l * 4 + wq) * 3 + 0];
                const float th  = qw[(l * 4 + wq) * 3 + 1];
                const float om  = qw[(l * 4 + wq) * 3 + 2];
                float st_, ct_, sa, ca, sb, cb;
                __sincosf(0.5f * th, &st_, &ct_);
                __sincosf(0.5f * (phi + om), &sa, &ca);
                __sincosf(0.5f * (phi - om), &sb, &cb);
                const int mask = 8 >> wq;
                const bool bit = (ql & mask) != 0;
                const float dr  = ca * ct_;
                const float di  = (bit ? sa : -sa) * ct_;
                const float orr = (bit ? cb : -cb) * st_;
                const float oi  = -sb * st_;
                const float pr = __shfl_xor(ar, mask);
                const float pi = __shfl_xor(ai, mask);
                const float nr = dr * ar - di * ai + orr * pr - oi * pi;
                const float ni = dr * ai + di * ar + orr * pi + oi * pr;
                ar = nr; ai = ni;
            }
            const int r = (l % 3) + 1;
#pragma unroll
            for (int wq = 0; wq < 4; ++wq) {
                const int mc  = 8 >> wq;
                const int mt  = 8 >> ((wq + r) % 4);
                const int src = (ql & mc) ? (ql ^ mt) : ql;
                ar = __shfl(ar, grp | src);
                ai = __shfl(ai, grp | src);
            }
        }
        const float prob = ar * ar + ai * ai;
        float coeff = 0.0f;
#pragma unroll
        for (int wq = 0; wq < 4; ++wq) {
            const float sgn = (ql & (8 >> wq)) ? -1.0f : 1.0f;
            coeff = fmaf(sgn, Wo[wq], coeff);
        }
        float v = prob * coeff;
        v += __shfl_xor(v, 1);
        v += __shfl_xor(v, 2);
        v += __shfl_xor(v, 4);
        v += __shfl_xor(v, 8);
        if (ql == 0) out[blockIdx.x * SPB + sm] = v + bo[0];
    }
}

extern "C" void kernel_launch(void* const* d_in, const int* in_sizes, int n_in,
                              void* d_out, int out_size, void* d_ws, size_t ws_size,
                              hipStream_t stream) {
    const float* x    = (const float*)d_in[0];
    const float* W_ih = (const float*)d_in[1];
    const float* W_hh = (const float*)d_in[2];
    const float* b_ih = (const float*)d_in[3];
    const float* b_hh = (const float*)d_in[4];
    const float* Wp   = (const float*)d_in[5];
    const float* bp   = (const float*)d_in[6];
    const float* qw   = (const float*)d_in[7];
    const float* Wo   = (const float*)d_in[8];
    const float* bo   = (const float*)d_in[9];
    float* out = (float*)d_out;

    const int B = in_sizes[0] / TSTEPS;
    hybrid_lstm_stag<<<B / SPB, THREADS, 0, stream>>>(x, W_ih, W_hh, b_ih, b_hh,
                                                      Wp, bp, qw, Wo, bo, out);
}